// Round 1
// baseline (251.693 us; speedup 1.0000x reference)
//
#include <hip/hip_runtime.h>

// PositionalEncoding: out = emb * sqrt(1024) + pe[:S] (broadcast over B),
// plus doc_emb = masked cumsum of (src_org == 49) along S per column.
// Outputs concatenated in d_out: out [4096*8*1024] then doc [4096*8].

constexpr int S_LEN   = 4096;
constexpr int B_COLS  = 8;
constexpr int DIM     = 1024;
constexpr int SPLIT   = 49;
constexpr int THREADS = 256;
constexpr int EW_BLOCKS = 2048;   // grid-stride elementwise blocks

__global__ __launch_bounds__(THREADS)
void pe_fused_kernel(const float* __restrict__ emb,
                     const int*   __restrict__ src,
                     const float* __restrict__ pe,
                     float* __restrict__ out,
                     float* __restrict__ doc)
{
    if (blockIdx.x < EW_BLOCKS) {
        // ---------- elementwise: out = emb*32 + pe[s,:]  (float4) ----------
        const float scale = 32.0f;  // sqrt(1024)
        const size_t n4     = (size_t)S_LEN * B_COLS * DIM / 4;   // 8,388,608
        const size_t stride = (size_t)EW_BLOCKS * THREADS;
        const float4* __restrict__ emb4 = reinterpret_cast<const float4*>(emb);
        float4* __restrict__ out4       = reinterpret_cast<float4*>(out);

        for (size_t i = (size_t)blockIdx.x * THREADS + threadIdx.x; i < n4; i += stride) {
            const size_t i0 = i << 2;                   // flat float index
            const size_t s  = i0 >> 13;                 // / (B*DIM) = /8192
            const size_t d  = i0 & (size_t)(DIM - 1);   // % 1024 (float4-aligned)
            float4 e = emb4[i];
            float4 p = *reinterpret_cast<const float4*>(pe + s * DIM + d);
            float4 o;
            o.x = fmaf(e.x, scale, p.x);
            o.y = fmaf(e.y, scale, p.y);
            o.z = fmaf(e.z, scale, p.z);
            o.w = fmaf(e.w, scale, p.w);
            out4[i] = o;
        }
    } else {
        // ---------- doc segment scan: one block per batch column ----------
        const int b = blockIdx.x - EW_BLOCKS;
        const int t = threadIdx.x;
        constexpr int PER = S_LEN / THREADS;            // 16 positions/thread
        const int base = t * PER;

        // indicator m[j] for positions base..base+PER, +1 lookahead for m_next
        int m[PER + 1];
        #pragma unroll
        for (int j = 0; j <= PER; ++j) {
            const int s = base + j;
            m[j] = (s < S_LEN && src[s * B_COLS + b] == SPLIT) ? 1 : 0;
        }

        int local = 0;
        #pragma unroll
        for (int j = 0; j < PER; ++j) local += m[j];

        // wave64 inclusive scan of per-thread sums
        int v = local;
        #pragma unroll
        for (int off = 1; off < 64; off <<= 1) {
            const int u = __shfl_up(v, off, 64);
            if ((t & 63) >= off) v += u;
        }

        __shared__ int wsum[THREADS / 64];
        if ((t & 63) == 63) wsum[t >> 6] = v;
        __syncthreads();

        int excl = v - local;                            // exclusive within wave
        for (int w = 0; w < (t >> 6); ++w) excl += wsum[w];

        int cum = excl;
        #pragma unroll
        for (int j = 0; j < PER; ++j) {
            cum += m[j];
            doc[(base + j) * B_COLS + b] = m[j + 1] ? 0.0f : (float)cum;
        }
    }
}

extern "C" void kernel_launch(void* const* d_in, const int* in_sizes, int n_in,
                              void* d_out, int out_size, void* d_ws, size_t ws_size,
                              hipStream_t stream) {
    const float* emb = (const float*)d_in[0];   // [4096, 8, 1024] f32
    const int*   src = (const int*)d_in[1];     // [4096, 8, 1]    i32
    const float* pe  = (const float*)d_in[2];   // [5000, 1, 1024] f32

    float* out = (float*)d_out;                                  // 33,554,432 f32
    float* doc = out + (size_t)S_LEN * B_COLS * DIM;             // + 32,768 f32

    pe_fused_kernel<<<EW_BLOCKS + B_COLS, THREADS, 0, stream>>>(emb, src, pe, out, doc);
}

// Round 2
// 239.438 us; speedup vs baseline: 1.0512x; 1.0512x over previous
//
#include <hip/hip_runtime.h>

// PositionalEncoding: out = emb * sqrt(1024) + pe[:S] (broadcast over B),
// plus doc_emb = masked cumsum of (src_org == 49) along S per column.
// Outputs concatenated in d_out: out [4096*8*1024] then doc [4096*8].
//
// R2 structure: block-per-row. Block s owns slab [s,:,:] (32KB contiguous).
// Thread t keeps pe4[s*256+t] in a register (8x reuse, zero L2 pe stream),
// issues 8 independent nontemporal loads (ILP) then 8 fma+NT stores.

constexpr int S_LEN   = 4096;
constexpr int B_COLS  = 8;
constexpr int DIM     = 1024;
constexpr int SPLIT   = 49;
constexpr int THREADS = 256;

typedef float f32x4 __attribute__((ext_vector_type(4)));

__global__ __launch_bounds__(THREADS)
void pe_row_kernel(const float* __restrict__ emb,
                   const int*   __restrict__ src,
                   const float* __restrict__ pe,
                   float* __restrict__ out,
                   float* __restrict__ doc)
{
    if (blockIdx.x < S_LEN) {
        // ---------- elementwise: one block per sequence row ----------
        const int s = blockIdx.x;
        const int t = threadIdx.x;                      // float4 lane within the dim
        const float scale = 32.0f;                      // sqrt(1024)

        const f32x4* __restrict__ emb4 = reinterpret_cast<const f32x4*>(emb);
        const f32x4* __restrict__ pe4  = reinterpret_cast<const f32x4*>(pe);
        f32x4* __restrict__ out4       = reinterpret_cast<f32x4*>(out);

        const f32x4 p = pe4[(size_t)s * (DIM / 4) + t];           // once, stays in VGPRs
        const size_t base = (size_t)s * (B_COLS * DIM / 4) + t;   // [s, b=0, d4=t]

        f32x4 e[B_COLS];
        #pragma unroll
        for (int b = 0; b < B_COLS; ++b)
            e[b] = __builtin_nontemporal_load(&emb4[base + (size_t)b * (DIM / 4)]);

        #pragma unroll
        for (int b = 0; b < B_COLS; ++b) {
            f32x4 o;
            o.x = fmaf(e[b].x, scale, p.x);
            o.y = fmaf(e[b].y, scale, p.y);
            o.z = fmaf(e[b].z, scale, p.z);
            o.w = fmaf(e[b].w, scale, p.w);
            __builtin_nontemporal_store(o, &out4[base + (size_t)b * (DIM / 4)]);
        }
    } else {
        // ---------- doc segment scan: one block per batch column ----------
        const int b = blockIdx.x - S_LEN;
        const int t = threadIdx.x;
        constexpr int PER = S_LEN / THREADS;            // 16 positions/thread
        const int base = t * PER;

        // indicator m[j] for positions base..base+PER, +1 lookahead for m_next
        int m[PER + 1];
        #pragma unroll
        for (int j = 0; j <= PER; ++j) {
            const int s = base + j;
            m[j] = (s < S_LEN && src[s * B_COLS + b] == SPLIT) ? 1 : 0;
        }

        int local = 0;
        #pragma unroll
        for (int j = 0; j < PER; ++j) local += m[j];

        // wave64 inclusive scan of per-thread sums
        int v = local;
        #pragma unroll
        for (int off = 1; off < 64; off <<= 1) {
            const int u = __shfl_up(v, off, 64);
            if ((t & 63) >= off) v += u;
        }

        __shared__ int wsum[THREADS / 64];
        if ((t & 63) == 63) wsum[t >> 6] = v;
        __syncthreads();

        int excl = v - local;                            // exclusive within wave
        for (int w = 0; w < (t >> 6); ++w) excl += wsum[w];

        int cum = excl;
        #pragma unroll
        for (int j = 0; j < PER; ++j) {
            cum += m[j];
            doc[(base + j) * B_COLS + b] = m[j + 1] ? 0.0f : (float)cum;
        }
    }
}

extern "C" void kernel_launch(void* const* d_in, const int* in_sizes, int n_in,
                              void* d_out, int out_size, void* d_ws, size_t ws_size,
                              hipStream_t stream) {
    const float* emb = (const float*)d_in[0];   // [4096, 8, 1024] f32
    const int*   src = (const int*)d_in[1];     // [4096, 8, 1]    i32
    const float* pe  = (const float*)d_in[2];   // [5000, 1, 1024] f32

    float* out = (float*)d_out;                                  // 33,554,432 f32
    float* doc = out + (size_t)S_LEN * B_COLS * DIM;             // + 32,768 f32

    pe_row_kernel<<<S_LEN + B_COLS, THREADS, 0, stream>>>(emb, src, pe, out, doc);
}